// Round 4
// baseline (726.454 us; speedup 1.0000x reference)
//
#include <hip/hip_runtime.h>
#include <math.h>

#define N_NODES   100000
#define N_EDGES   1600000
#define N_FEAT    64
#define HIDDEN    64
#define BIOPRINT  2048
#define N_GRAPHS  1024

#define SCAN_BLK  1024
#define N_SCAN_BLOCKS ((N_NODES + SCAN_BLK - 1) / SCAN_BLK)   // 98

// ---------------- degree / normalization ----------------

__global__ void k_deg(const int* __restrict__ dst, int* __restrict__ deg, int n) {
    int i = blockIdx.x * blockDim.x + threadIdx.x;
    if (i < n) atomicAdd(&deg[dst[i]], 1);
}

__global__ void k_dinv_cnt(const int* __restrict__ deg, float* __restrict__ dinv,
                           const int* __restrict__ batch, float* __restrict__ cnt, int n) {
    int i = blockIdx.x * blockDim.x + threadIdx.x;
    if (i < n) {
        dinv[i] = rsqrtf((float)deg[i] + 1.0f);
        atomicAdd(&cnt[batch[i]], 1.0f);
    }
}

// ---------------- CSR build ----------------

__global__ __launch_bounds__(SCAN_BLK) void k_scan1(
        const int* __restrict__ deg, int* __restrict__ incl,
        int* __restrict__ bsum, int n) {
    __shared__ int tmp[SCAN_BLK];
    int t = threadIdx.x;
    int i = blockIdx.x * SCAN_BLK + t;
    int v = (i < n) ? deg[i] : 0;
    tmp[t] = v;
    __syncthreads();
    for (int off = 1; off < SCAN_BLK; off <<= 1) {
        int u = (t >= off) ? tmp[t - off] : 0;
        __syncthreads();
        tmp[t] += u;
        __syncthreads();
    }
    if (i < n) incl[i] = tmp[t];
    if (t == SCAN_BLK - 1) bsum[blockIdx.x] = tmp[t];
}

__global__ void k_scan2(int* __restrict__ bsum, int nb) {
    if (threadIdx.x == 0 && blockIdx.x == 0) {
        int run = 0;
        for (int b = 0; b < nb; ++b) { int v = bsum[b]; bsum[b] = run; run += v; }
    }
}

__global__ __launch_bounds__(SCAN_BLK) void k_scan3(
        int* __restrict__ rowptr, const int* __restrict__ deg,
        const int* __restrict__ bsum, int* __restrict__ cursor, int n) {
    int i = blockIdx.x * SCAN_BLK + threadIdx.x;
    if (i < n) {
        int ex = rowptr[i] - deg[i] + bsum[blockIdx.x];
        rowptr[i] = ex;
        cursor[i] = ex;
    }
    if (i == 0) rowptr[n] = N_EDGES;
}

// fill: one 4B store per edge (col index only — weights folded into hw' scaling)
__global__ void k_fill(const int* __restrict__ src, const int* __restrict__ dst,
                       int* __restrict__ cursor, int* __restrict__ col, int n) {
    int e = blockIdx.x * blockDim.x + threadIdx.x;
    if (e < n) {
        int s = src[e], d = dst[e];
        int pos = atomicAdd(&cursor[d], 1);
        col[pos] = s;
    }
}

// ---------------- layer-1 matmul: hw' = (x @ W) * dinv[row] ----------------
__global__ __launch_bounds__(256) void k_mm(
        const float* __restrict__ h, const float* __restrict__ W,
        const float* __restrict__ dinv, float* __restrict__ hw) {
    __shared__ float sW[64 * 64];
    __shared__ float sH[4 * 64];
    int t = threadIdx.x;
    const float4* W4 = (const float4*)W;
    float4* sW4 = (float4*)sW;
    for (int i = t; i < 1024; i += 256) sW4[i] = W4[i];
    int row0 = blockIdx.x * 4;
    {
        int r = t >> 6, j = t & 63;
        sH[r * 64 + j] = h[(row0 + r) * 64 + j];
    }
    __syncthreads();
    int r = t >> 6, j = t & 63;
    float sum = 0.0f;
#pragma unroll
    for (int k = 0; k < 64; ++k) sum = fmaf(sH[r * 64 + k], sW[k * 64 + j], sum);
    hw[(row0 + r) * 64 + j] = sum * dinv[row0 + r];
}

// ---------------- fused gather + relu + next matmul ----------------
// Block = 4 waves = 4 nodes. Wave: quarter q handles edge e+q with a float4
// row-slice load (4 edges in flight per superload). Butterfly-reduce across
// quarters. conv_i = dinv[i]*(sum_e hw'[col] + hw'[i]) + b. No inter-wave
// barrier after W staging (each wave's mm reads only its own sA row).
__global__ __launch_bounds__(256) void k_gmm(
        const int* __restrict__ rowptr, const int* __restrict__ col,
        const float* __restrict__ dinv, const float* __restrict__ b,
        const float* __restrict__ hw_in, const float* __restrict__ W,
        float* __restrict__ hw_out) {
    __shared__ float sW[64 * 64];
    __shared__ float sA[4 * 64];
    int t = threadIdx.x;
    const float4* W4 = (const float4*)W;
    float4* sW4 = (float4*)sW;
    for (int i = t; i < 1024; i += 256) sW4[i] = W4[i];
    __syncthreads();

    int wave = t >> 6, lane = t & 63;
    int q = lane >> 4, sub = lane & 15;
    int i = blockIdx.x * 4 + wave;
    float di = dinv[i];
    int rs = rowptr[i], re = rowptr[i + 1];
    const float4* hwv = (const float4*)hw_in;
    float4 self4 = hwv[i * 16 + sub];
    float4 b4 = ((const float4*)b)[sub];

    float ax = 0.f, ay = 0.f, az = 0.f, aw = 0.f;
    int e = rs;
    for (; e + 8 <= re; e += 8) {
        int s0 = col[e + q];
        int s1 = col[e + 4 + q];
        float4 v0 = hwv[s0 * 16 + sub];
        float4 v1 = hwv[s1 * 16 + sub];
        ax += v0.x; ay += v0.y; az += v0.z; aw += v0.w;
        ax += v1.x; ay += v1.y; az += v1.z; aw += v1.w;
    }
    if (e + 4 <= re) {
        int s0 = col[e + q];
        float4 v0 = hwv[s0 * 16 + sub];
        ax += v0.x; ay += v0.y; az += v0.z; aw += v0.w;
        e += 4;
    }
    if (e + q < re) {
        int s0 = col[e + q];
        float4 v0 = hwv[s0 * 16 + sub];
        ax += v0.x; ay += v0.y; az += v0.z; aw += v0.w;
    }
    // reduce across quarters (all lanes end with full sums)
    ax += __shfl_xor(ax, 16); ay += __shfl_xor(ay, 16);
    az += __shfl_xor(az, 16); aw += __shfl_xor(aw, 16);
    ax += __shfl_xor(ax, 32); ay += __shfl_xor(ay, 32);
    az += __shfl_xor(az, 32); aw += __shfl_xor(aw, 32);

    float4 r;
    r.x = fmaxf(fmaf(di, ax + self4.x, b4.x), 0.f);
    r.y = fmaxf(fmaf(di, ay + self4.y, b4.y), 0.f);
    r.z = fmaxf(fmaf(di, az + self4.z, b4.z), 0.f);
    r.w = fmaxf(fmaf(di, aw + self4.w, b4.w), 0.f);
    if (q == 0) ((float4*)&sA[wave * 64])[sub] = r;

    // per-wave mm: out[j] = sum_k sA_row[k] * W[k][j]  (same-wave LDS ordering)
    const float4* sA4 = (const float4*)&sA[wave * 64];
    float sum = 0.f;
#pragma unroll
    for (int k4 = 0; k4 < 16; ++k4) {
        float4 a4 = sA4[k4];
        sum = fmaf(a4.x, sW[(k4 * 4 + 0) * 64 + lane], sum);
        sum = fmaf(a4.y, sW[(k4 * 4 + 1) * 64 + lane], sum);
        sum = fmaf(a4.z, sW[(k4 * 4 + 2) * 64 + lane], sum);
        sum = fmaf(a4.w, sW[(k4 * 4 + 3) * 64 + lane], sum);
    }
    hw_out[i * 64 + lane] = sum * di;   // pre-scale for next layer's gather
}

// ---------------- fused gather (layer 3, no relu) + mean-pool atomics ----------------
__global__ __launch_bounds__(256) void k_gpool(
        const int* __restrict__ rowptr, const int* __restrict__ col,
        const float* __restrict__ dinv, const float* __restrict__ b,
        const float* __restrict__ hw_in, const int* __restrict__ batch,
        float* __restrict__ pooled) {
    int t = threadIdx.x;
    int wave = t >> 6, lane = t & 63;
    int q = lane >> 4, sub = lane & 15;
    int i = blockIdx.x * 4 + wave;
    float di = dinv[i];
    int rs = rowptr[i], re = rowptr[i + 1];
    const float4* hwv = (const float4*)hw_in;
    float4 self4 = hwv[i * 16 + sub];
    float4 b4 = ((const float4*)b)[sub];

    float ax = 0.f, ay = 0.f, az = 0.f, aw = 0.f;
    int e = rs;
    for (; e + 8 <= re; e += 8) {
        int s0 = col[e + q];
        int s1 = col[e + 4 + q];
        float4 v0 = hwv[s0 * 16 + sub];
        float4 v1 = hwv[s1 * 16 + sub];
        ax += v0.x; ay += v0.y; az += v0.z; aw += v0.w;
        ax += v1.x; ay += v1.y; az += v1.z; aw += v1.w;
    }
    if (e + 4 <= re) {
        int s0 = col[e + q];
        float4 v0 = hwv[s0 * 16 + sub];
        ax += v0.x; ay += v0.y; az += v0.z; aw += v0.w;
        e += 4;
    }
    if (e + q < re) {
        int s0 = col[e + q];
        float4 v0 = hwv[s0 * 16 + sub];
        ax += v0.x; ay += v0.y; az += v0.z; aw += v0.w;
    }
    ax += __shfl_xor(ax, 16); ay += __shfl_xor(ay, 16);
    az += __shfl_xor(az, 16); aw += __shfl_xor(aw, 16);
    ax += __shfl_xor(ax, 32); ay += __shfl_xor(ay, 32);
    az += __shfl_xor(az, 32); aw += __shfl_xor(aw, 32);

    if (q == 0) {
        int g = batch[i];
        float* p = &pooled[g * 64 + sub * 4];
        atomicAdd(p + 0, fmaf(di, ax + self4.x, b4.x));
        atomicAdd(p + 1, fmaf(di, ay + self4.y, b4.y));
        atomicAdd(p + 2, fmaf(di, az + self4.z, b4.z));
        atomicAdd(p + 3, fmaf(di, aw + self4.w, b4.w));
    }
}

// ---------------- dense + softmax + threshold: 4 graphs per block ----------------
__global__ __launch_bounds__(256) void k_dense(
        const float* __restrict__ pooled, const float* __restrict__ cnt,
        const float* __restrict__ Wd, const float* __restrict__ bd,
        float* __restrict__ out) {
    __shared__ float sp[4][64];
    __shared__ float red[4][4];
    int t = threadIdx.x;
    int g0 = blockIdx.x * 4;
    {
        int g = t >> 6, k = t & 63;
        float c = cnt[g0 + g];
        sp[g][k] = pooled[(g0 + g) * 64 + k] / fmaxf(c, 1.0f);
    }
    __syncthreads();

    float acc[4][8];
#pragma unroll
    for (int r = 0; r < 8; ++r) {
        float bv = bd[r * 256 + t];
#pragma unroll
        for (int g = 0; g < 4; ++g) acc[g][r] = bv;
    }
    for (int k = 0; k < 64; ++k) {
        float w[8];
#pragma unroll
        for (int r = 0; r < 8; ++r) w[r] = Wd[k * BIOPRINT + r * 256 + t];
#pragma unroll
        for (int g = 0; g < 4; ++g) {
            float h = sp[g][k];
#pragma unroll
            for (int r = 0; r < 8; ++r) acc[g][r] = fmaf(h, w[r], acc[g][r]);
        }
    }
    int wave = t >> 6, lane = t & 63;
    // per-graph max
    float gm[4];
#pragma unroll
    for (int g = 0; g < 4; ++g) {
        float m = acc[g][0];
#pragma unroll
        for (int r = 1; r < 8; ++r) m = fmaxf(m, acc[g][r]);
#pragma unroll
        for (int off = 32; off > 0; off >>= 1) m = fmaxf(m, __shfl_xor(m, off));
        if (lane == 0) red[g][wave] = m;
    }
    __syncthreads();
#pragma unroll
    for (int g = 0; g < 4; ++g)
        gm[g] = fmaxf(fmaxf(red[g][0], red[g][1]), fmaxf(red[g][2], red[g][3]));
    __syncthreads();
    // per-graph sum of exp
    float gs[4];
#pragma unroll
    for (int g = 0; g < 4; ++g) {
        float s = 0.f;
#pragma unroll
        for (int r = 0; r < 8; ++r) { acc[g][r] = expf(acc[g][r] - gm[g]); s += acc[g][r]; }
#pragma unroll
        for (int off = 32; off > 0; off >>= 1) s += __shfl_xor(s, off);
        if (lane == 0) red[g][wave] = s;
    }
    __syncthreads();
#pragma unroll
    for (int g = 0; g < 4; ++g)
        gs[g] = red[g][0] + red[g][1] + red[g][2] + red[g][3];
#pragma unroll
    for (int g = 0; g < 4; ++g)
#pragma unroll
        for (int r = 0; r < 8; ++r) {
            float p = acc[g][r] / gs[g];
            out[(size_t)(g0 + g) * BIOPRINT + r * 256 + t] = (p >= 0.5f) ? 1.0f : 0.0f;
        }
}

// ---------------- launch ----------------

extern "C" void kernel_launch(void* const* d_in, const int* in_sizes, int n_in,
                              void* d_out, int out_size, void* d_ws, size_t ws_size,
                              hipStream_t stream) {
    const float* x     = (const float*)d_in[0];
    const int*   ei    = (const int*)d_in[1];      // [2][N_EDGES]: src, dst
    const int*   batch = (const int*)d_in[2];
    const float* W1 = (const float*)d_in[3];
    const float* b1 = (const float*)d_in[4];
    const float* W2 = (const float*)d_in[5];
    const float* b2 = (const float*)d_in[6];
    const float* W3 = (const float*)d_in[7];
    const float* b3 = (const float*)d_in[8];
    const float* Wd = (const float*)d_in[9];
    const float* bd = (const float*)d_in[10];
    float* out = (float*)d_out;

    const int* src = ei;
    const int* dst = ei + N_EDGES;

    char* ws = (char*)d_ws;
    size_t off = 0;
    auto alloc = [&](size_t bytes) {
        void* p = ws + off;
        off += (bytes + 255) & ~(size_t)255;
        return p;
    };
    int*   deg    = (int*)alloc(N_NODES * sizeof(int));
    float* dinv   = (float*)alloc(N_NODES * sizeof(float));
    float* pooled = (float*)alloc(N_GRAPHS * HIDDEN * sizeof(float));
    float* cnt    = (float*)alloc(N_GRAPHS * sizeof(float));
    int*   rowptr = (int*)alloc((N_NODES + 1) * sizeof(int));
    int*   bsum   = (int*)alloc(N_SCAN_BLOCKS * sizeof(int));
    int*   cursor = (int*)alloc(N_NODES * sizeof(int));
    int*   col    = (int*)alloc((size_t)N_EDGES * sizeof(int));
    float* bufA   = (float*)alloc((size_t)N_NODES * HIDDEN * sizeof(float));
    float* bufB   = (float*)alloc((size_t)N_NODES * HIDDEN * sizeof(float));

    hipMemsetAsync(deg, 0, N_NODES * sizeof(int), stream);
    hipMemsetAsync(pooled, 0, N_GRAPHS * HIDDEN * sizeof(float), stream);
    hipMemsetAsync(cnt, 0, N_GRAPHS * sizeof(float), stream);

    k_deg<<<(N_EDGES + 255) / 256, 256, 0, stream>>>(dst, deg, N_EDGES);
    k_dinv_cnt<<<(N_NODES + 255) / 256, 256, 0, stream>>>(deg, dinv, batch, cnt, N_NODES);

    k_scan1<<<N_SCAN_BLOCKS, SCAN_BLK, 0, stream>>>(deg, rowptr, bsum, N_NODES);
    k_scan2<<<1, 64, 0, stream>>>(bsum, N_SCAN_BLOCKS);
    k_scan3<<<N_SCAN_BLOCKS, SCAN_BLK, 0, stream>>>(rowptr, deg, bsum, cursor, N_NODES);
    k_fill<<<(N_EDGES + 255) / 256, 256, 0, stream>>>(src, dst, cursor, col, N_EDGES);

    const int mm_grid = N_NODES / 4;          // 25000
    // layer 1: hw1' = (x @ W1) * dinv -> A
    k_mm<<<mm_grid, 256, 0, stream>>>(x, W1, dinv, bufA);
    // conv1 + relu + @W2 (scaled) -> B
    k_gmm<<<mm_grid, 256, 0, stream>>>(rowptr, col, dinv, b1, bufA, W2, bufB);
    // conv2 + relu + @W3 (scaled) -> A
    k_gmm<<<mm_grid, 256, 0, stream>>>(rowptr, col, dinv, b2, bufB, W3, bufA);
    // conv3 (no relu) + mean-pool atomics
    k_gpool<<<mm_grid, 256, 0, stream>>>(rowptr, col, dinv, b3, bufA, batch, pooled);
    // dense + softmax + threshold (4 graphs/block)
    k_dense<<<N_GRAPHS / 4, 256, 0, stream>>>(pooled, cnt, Wd, bd, out);
}